// Round 1
// baseline (892.032 us; speedup 1.0000x reference)
//
#include <hip/hip_runtime.h>

#define NN 20000
#define NE 320000
#define NG 256

// ---------------- CSR build ----------------

__global__ __launch_bounds__(256) void hist_kernel(const int* __restrict__ dst,
                                                   int* __restrict__ counts) {
  int e = blockIdx.x * 256 + threadIdx.x;
  if (e < NE) atomicAdd(&counts[dst[e]], 1);
}

// single-block exclusive scan over NN counts -> rowptr[NN+1]
__global__ __launch_bounds__(1024) void scan_kernel(const int* __restrict__ counts,
                                                    int* __restrict__ rowptr) {
  __shared__ int buf[1024];
  __shared__ int carry_s;
  int t = threadIdx.x;
  if (t == 0) carry_s = 0;
  __syncthreads();
  for (int base = 0; base < NN; base += 1024) {
    int v = (base + t < NN) ? counts[base + t] : 0;
    buf[t] = v;
    __syncthreads();
    for (int off = 1; off < 1024; off <<= 1) {
      int add = (t >= off) ? buf[t - off] : 0;
      __syncthreads();
      buf[t] += add;
      __syncthreads();
    }
    int incl = buf[t];
    int carry = carry_s;
    if (base + t < NN) rowptr[base + t] = carry + incl - v;
    __syncthreads();
    if (t == 1023) carry_s = carry + incl;
    __syncthreads();
  }
  if (t == 0) rowptr[NN] = carry_s;
}

__global__ __launch_bounds__(256) void scatter_kernel(const int* __restrict__ src,
                                                      const int* __restrict__ dst,
                                                      const int* __restrict__ rowptr,
                                                      int* __restrict__ cur,
                                                      int* __restrict__ srcs) {
  int e = blockIdx.x * 256 + threadIdx.x;
  if (e < NE) {
    int d = dst[e];
    int pos = rowptr[d] + atomicAdd(&cur[d], 1);
    srcs[pos] = src[e];
  }
}

// ---------------- GAT conv ----------------

// h = x @ W  [NN,64]; a_src[n][hd] = sum_c h*att_src ; a_dst likewise.
// one wave per row (block=256 -> 4 rows), lane = output channel.
__global__ __launch_bounds__(256) void gemm_attn_kernel(
    const float* __restrict__ x, const float* __restrict__ W,
    const float* __restrict__ att_src, const float* __restrict__ att_dst,
    float* __restrict__ h, float* __restrict__ a_src, float* __restrict__ a_dst,
    int H) {
  __shared__ float xs[4][64];
  int t = threadIdx.x;
  int lr = t >> 6;
  int c = t & 63;
  int n = blockIdx.x * 4 + lr;
  xs[lr][c] = x[n * 64 + c];
  __syncthreads();
  float acc = 0.f;
#pragma unroll
  for (int k = 0; k < 64; ++k) acc += xs[lr][k] * W[k * 64 + c];
  h[n * 64 + c] = acc;
  float ts = acc * att_src[c];
  float td = acc * att_dst[c];
  int gs = 64 / H;  // 8 (H=8) or 64 (H=1)
  for (int off = 1; off < gs; off <<= 1) {
    ts += __shfl_xor(ts, off);
    td += __shfl_xor(td, off);
  }
  if ((c & (gs - 1)) == 0) {
    int hd = c / gs;
    a_src[n * H + hd] = ts;
    a_dst[n * H + hd] = td;
  }
}

// segment softmax + weighted aggregation; one wave per dst node, lane = channel.
// self loop handled implicitly (not in CSR). exp without max-shift (shift-invariant).
__global__ __launch_bounds__(256) void agg_kernel(
    const float* __restrict__ h, const float* __restrict__ a_src,
    const float* __restrict__ a_dst, const int* __restrict__ rowptr,
    const int* __restrict__ srcs, const float* __restrict__ bias,
    float* __restrict__ out, int H, int do_relu) {
  int t = threadIdx.x;
  int i = blockIdx.x * 4 + (t >> 6);
  int c = t & 63;
  int hd = (H == 8) ? (c >> 3) : 0;
  float ad = a_dst[i * H + hd];
  // self loop
  float l = a_src[i * H + hd] + ad;
  l = (l > 0.f) ? l : 0.2f * l;
  float w = expf(l);
  float denom = w;
  float acc = w * h[i * 64 + c];
  int jend = rowptr[i + 1];
  for (int j = rowptr[i]; j < jend; ++j) {
    int s = srcs[j];
    float as = a_src[s * H + hd];
    float ll = as + ad;
    ll = (ll > 0.f) ? ll : 0.2f * ll;
    float ww = expf(ll);
    denom += ww;
    acc += ww * h[s * 64 + c];
  }
  float o = acc / denom + bias[c];
  if (do_relu) o = fmaxf(o, 0.f);
  out[i * 64 + c] = o;
}

// ---------------- pooling + readout ----------------

__global__ __launch_bounds__(256) void pool_kernel(const float* __restrict__ x,
                                                   const int* __restrict__ batch,
                                                   float* __restrict__ g_sum,
                                                   float* __restrict__ cnt) {
  int t = threadIdx.x;
  int n = blockIdx.x * 4 + (t >> 6);
  int c = t & 63;
  int b = batch[n];
  atomicAdd(&g_sum[b * 64 + c], x[n * 64 + c]);
  if (c == 0) atomicAdd(&cnt[b], 1.f);
}

__global__ __launch_bounds__(64) void readout_kernel(
    const float* __restrict__ g_sum, const float* __restrict__ cnt,
    const float* __restrict__ Wm1, const float* __restrict__ bm1,
    const float* __restrict__ Wm2, const float* __restrict__ bm2,
    float* __restrict__ out) {
  int g = blockIdx.x;
  int t = threadIdx.x;
  float cv = fmaxf(cnt[g], 1.f);
  float gv = g_sum[g * 64 + t] / cv;
  float acc = 0.f;
#pragma unroll
  for (int k = 0; k < 64; ++k) {
    float bk = __shfl(gv, k);
    if (t < 32) acc += bk * Wm1[k * 32 + t];
  }
  float m = 0.f;
  if (t < 32) {
    float hid = fmaxf(acc + bm1[t], 0.f);
    m = hid * Wm2[t];
  }
  for (int off = 32; off >= 1; off >>= 1) m += __shfl_xor(m, off);
  if (t == 0) out[g] = m + bm2[0];
}

// ---------------- launch ----------------

extern "C" void kernel_launch(void* const* d_in, const int* in_sizes, int n_in,
                              void* d_out, int out_size, void* d_ws, size_t ws_size,
                              hipStream_t stream) {
  const float* x0        = (const float*)d_in[0];
  const int*   edge_idx  = (const int*)d_in[1];
  const int*   batch     = (const int*)d_in[3];
  const int*   dis_idx   = (const int*)d_in[6];
  const float* W1  = (const float*)d_in[7];
  const float* as1 = (const float*)d_in[8];
  const float* ad1 = (const float*)d_in[9];
  const float* b1  = (const float*)d_in[10];
  const float* W2  = (const float*)d_in[11];
  const float* as2 = (const float*)d_in[12];
  const float* ad2 = (const float*)d_in[13];
  const float* b2  = (const float*)d_in[14];
  const float* Wm1 = (const float*)d_in[19];
  const float* bm1 = (const float*)d_in[20];
  const float* Wm2 = (const float*)d_in[21];
  const float* bm2 = (const float*)d_in[22];
  float* out = (float*)d_out;

  char* ws = (char*)d_ws;
  size_t off = 0;
  auto alloc = [&](size_t bytes) {
    void* p = ws + off;
    off += (bytes + 255) & ~(size_t)255;
    return p;
  };
  float* bufA   = (float*)alloc(NN * 64 * 4);
  float* bufC   = (float*)alloc(NN * 64 * 4);
  float* bufH   = (float*)alloc(NN * 64 * 4);
  float* a_src  = (float*)alloc(NN * 8 * 4);
  float* a_dst  = (float*)alloc(NN * 8 * 4);
  int* rowptr_d = (int*)alloc((NN + 1) * 4);
  int* srcs_d   = (int*)alloc(NE * 4);
  int* rowptr_e = (int*)alloc((NN + 1) * 4);
  int* srcs_e   = (int*)alloc(NE * 4);
  int* cnts     = (int*)alloc(NN * 4);
  float* g_sum  = (float*)alloc(NG * 64 * 4);
  float* gcnt   = (float*)alloc(NG * 4);

  const int EB = (NE + 255) / 256;

  // CSR for dis_index (row0 = src, row1 = dst)
  hipMemsetAsync(cnts, 0, NN * 4, stream);
  hist_kernel<<<EB, 256, 0, stream>>>(dis_idx + NE, cnts);
  scan_kernel<<<1, 1024, 0, stream>>>(cnts, rowptr_d);
  hipMemsetAsync(cnts, 0, NN * 4, stream);
  scatter_kernel<<<EB, 256, 0, stream>>>(dis_idx, dis_idx + NE, rowptr_d, cnts, srcs_d);

  // CSR for edge_index
  hipMemsetAsync(cnts, 0, NN * 4, stream);
  hist_kernel<<<EB, 256, 0, stream>>>(edge_idx + NE, cnts);
  scan_kernel<<<1, 1024, 0, stream>>>(cnts, rowptr_e);
  hipMemsetAsync(cnts, 0, NN * 4, stream);
  scatter_kernel<<<EB, 256, 0, stream>>>(edge_idx, edge_idx + NE, rowptr_e, cnts, srcs_e);

  const int NB = NN / 4;  // 5000 blocks of 256 (4 rows each), exact

  const float* cur = x0;
  float* pp[2] = {bufA, bufC};
  int pi = 0;

  for (int layer = 0; layer < 3; ++layer) {
    // conv1 on dis_index (H=8, relu)
    gemm_attn_kernel<<<NB, 256, 0, stream>>>(cur, W1, as1, ad1, bufH, a_src, a_dst, 8);
    agg_kernel<<<NB, 256, 0, stream>>>(bufH, a_src, a_dst, rowptr_d, srcs_d, b1, pp[pi], 8, 1);
    cur = pp[pi]; pi ^= 1;
    // conv2 on dis_index (H=1)
    gemm_attn_kernel<<<NB, 256, 0, stream>>>(cur, W2, as2, ad2, bufH, a_src, a_dst, 1);
    agg_kernel<<<NB, 256, 0, stream>>>(bufH, a_src, a_dst, rowptr_d, srcs_d, b2, pp[pi], 1, 0);
    cur = pp[pi]; pi ^= 1;
    // conv1 on edge_index (H=8, relu)
    gemm_attn_kernel<<<NB, 256, 0, stream>>>(cur, W1, as1, ad1, bufH, a_src, a_dst, 8);
    agg_kernel<<<NB, 256, 0, stream>>>(bufH, a_src, a_dst, rowptr_e, srcs_e, b1, pp[pi], 8, 1);
    cur = pp[pi]; pi ^= 1;
    // conv2 on edge_index (H=1)
    gemm_attn_kernel<<<NB, 256, 0, stream>>>(cur, W2, as2, ad2, bufH, a_src, a_dst, 1);
    agg_kernel<<<NB, 256, 0, stream>>>(bufH, a_src, a_dst, rowptr_e, srcs_e, b2, pp[pi], 1, 0);
    cur = pp[pi]; pi ^= 1;
  }

  // global mean pool + readout MLP
  hipMemsetAsync(g_sum, 0, NG * 64 * 4, stream);
  hipMemsetAsync(gcnt, 0, NG * 4, stream);
  pool_kernel<<<NB, 256, 0, stream>>>(cur, batch, g_sum, gcnt);
  readout_kernel<<<NG, 64, 0, stream>>>(g_sum, gcnt, Wm1, bm1, Wm2, bm2, out);
}

// Round 2
// 532.774 us; speedup vs baseline: 1.6743x; 1.6743x over previous
//
#include <hip/hip_runtime.h>

#define NN 20000
#define NE 320000
#define NG 256

// ---------------- CSR build ----------------

__global__ __launch_bounds__(256) void hist_kernel(const int* __restrict__ dst,
                                                   int* __restrict__ counts) {
  int e = blockIdx.x * 256 + threadIdx.x;
  if (e < NE) atomicAdd(&counts[dst[e]], 1);
}

// single-block scan over NN counts -> rowptr[NN+1]; wave-shfl based (4 barriers/chunk)
__global__ __launch_bounds__(1024) void scan_kernel(const int* __restrict__ counts,
                                                    int* __restrict__ rowptr) {
  __shared__ int wsum[16];
  __shared__ int carry_s;
  int t = threadIdx.x;
  int lane = t & 63;
  int w = t >> 6;
  if (t == 0) carry_s = 0;
  __syncthreads();
  for (int base = 0; base < NN; base += 1024) {
    int v = (base + t < NN) ? counts[base + t] : 0;
    int incl = v;
#pragma unroll
    for (int off = 1; off < 64; off <<= 1) {
      int g = __shfl_up(incl, off);
      if (lane >= off) incl += g;
    }
    if (lane == 63) wsum[w] = incl;
    __syncthreads();
    if (w == 0 && lane < 16) {
      int s = wsum[lane];
#pragma unroll
      for (int off = 1; off < 16; off <<= 1) {
        int g = __shfl_up(s, off);
        if (lane >= off) s += g;
      }
      wsum[lane] = s;
    }
    __syncthreads();
    int woff = (w > 0) ? wsum[w - 1] : 0;
    int carry = carry_s;
    int tot = carry + woff + incl;
    if (base + t < NN) rowptr[base + t] = tot - v;  // exclusive
    __syncthreads();
    if (t == 1023) carry_s = tot;
    __syncthreads();
  }
  if (t == 0) rowptr[NN] = carry_s;
}

__global__ __launch_bounds__(256) void scatter_kernel(const int* __restrict__ src,
                                                      const int* __restrict__ dst,
                                                      const int* __restrict__ rowptr,
                                                      int* __restrict__ cur,
                                                      int* __restrict__ srcs) {
  int e = blockIdx.x * 256 + threadIdx.x;
  if (e < NE) {
    int d = dst[e];
    int pos = rowptr[d] + atomicAdd(&cur[d], 1);
    srcs[pos] = src[e];
  }
}

// ---------------- first GEMM + attention sums ----------------

__global__ __launch_bounds__(256) void gemm_attn_kernel(
    const float* __restrict__ x, const float* __restrict__ W,
    const float* __restrict__ att_src, const float* __restrict__ att_dst,
    float* __restrict__ h, float* __restrict__ a_src, float* __restrict__ a_dst,
    int H) {
  __shared__ float xs[4][64];
  __shared__ float ws[64 * 64];
  int t = threadIdx.x;
  int lr = t >> 6;
  int c = t & 63;
  int n = blockIdx.x * 4 + lr;
  const float4* W4 = (const float4*)W;
  float4* ws4 = (float4*)ws;
  for (int k = t; k < 1024; k += 256) ws4[k] = W4[k];
  xs[lr][c] = x[n * 64 + c];
  __syncthreads();
  float acc = 0.f;
#pragma unroll
  for (int k = 0; k < 64; ++k) acc = fmaf(xs[lr][k], ws[k * 64 + c], acc);
  h[n * 64 + c] = acc;
  float ts = acc * att_src[c];
  float td = acc * att_dst[c];
  int gs = 64 / H;
  for (int off = 1; off < gs; off <<= 1) {
    ts += __shfl_xor(ts, off);
    td += __shfl_xor(td, off);
  }
  if ((c & (gs - 1)) == 0) {
    int hd = c / gs;
    a_src[n * H + hd] = ts;
    a_dst[n * H + hd] = td;
  }
}

// ---------------- fused agg (+ optional next-conv GEMM/attn) ----------------
// One wave per dst node, lane = channel. 8-wide predicated edge loop for MLP.
// HN == 0: write final x. HN != 0: fuse h_next = (relu?)(out) @ Wn and attn sums.
template <int H, bool RELU, int HN>
__global__ __launch_bounds__(256) void agg_fused_kernel(
    const float* __restrict__ h, const float* __restrict__ a_src,
    const float* __restrict__ a_dst, const int* __restrict__ rowptr,
    const int* __restrict__ srcs, const float* __restrict__ bias,
    float* __restrict__ out, const float* __restrict__ Wn,
    const float* __restrict__ asn, const float* __restrict__ adn,
    float* __restrict__ a_src_n, float* __restrict__ a_dst_n) {
  extern __shared__ float ws[];
  int t = threadIdx.x;
  int i = blockIdx.x * 4 + (t >> 6);
  int c = t & 63;
  if (HN != 0) {
    const float4* W4 = (const float4*)Wn;
    float4* ws4 = (float4*)ws;
    for (int k = t; k < 1024; k += 256) ws4[k] = W4[k];
    __syncthreads();
  }
  int hd = (H == 8) ? (c >> 3) : 0;
  float ad = a_dst[i * H + hd];
  // self loop
  float l = a_src[i * H + hd] + ad;
  l = (l > 0.f) ? l : 0.2f * l;
  float w = __expf(l);
  float denom = w;
  float acc = w * h[i * 64 + c];
  int j0 = rowptr[i], jend = rowptr[i + 1];
  for (int j = j0; j < jend; j += 8) {
    int s[8];
    float as[8], hv[8];
#pragma unroll
    for (int u = 0; u < 8; ++u) {
      int jj = j + u;
      jj = (jj < jend) ? jj : (jend - 1);
      s[u] = srcs[jj];
    }
#pragma unroll
    for (int u = 0; u < 8; ++u) as[u] = a_src[s[u] * H + hd];
#pragma unroll
    for (int u = 0; u < 8; ++u) hv[u] = h[s[u] * 64 + c];
#pragma unroll
    for (int u = 0; u < 8; ++u) {
      float ll = as[u] + ad;
      ll = (ll > 0.f) ? ll : 0.2f * ll;
      float ww = __expf(ll);
      ww = (j + u < jend) ? ww : 0.f;
      denom += ww;
      acc = fmaf(ww, hv[u], acc);
    }
  }
  float o = acc / denom + bias[c];
  if (RELU) o = fmaxf(o, 0.f);
  if (HN == 0) {
    out[i * 64 + c] = o;
  } else {
    float acc2 = 0.f;
#pragma unroll
    for (int k = 0; k < 64; ++k) {
      float ok = __shfl(o, k);
      acc2 = fmaf(ok, ws[k * 64 + c], acc2);
    }
    out[i * 64 + c] = acc2;
    float ts = acc2 * asn[c];
    float td = acc2 * adn[c];
    const int gs = 64 / HN;
#pragma unroll
    for (int off = 1; off < gs; off <<= 1) {
      ts += __shfl_xor(ts, off);
      td += __shfl_xor(td, off);
    }
    if ((c & (gs - 1)) == 0) {
      int hdn = c / gs;
      a_src_n[i * HN + hdn] = ts;
      a_dst_n[i * HN + hdn] = td;
    }
  }
}

// ---------------- pooling + readout ----------------

// batch is sorted: each wave owns 32 contiguous nodes, register-accumulate,
// atomic flush only on graph-boundary change.
__global__ __launch_bounds__(256) void pool_kernel(const float* __restrict__ x,
                                                   const int* __restrict__ batch,
                                                   float* __restrict__ g_sum,
                                                   float* __restrict__ cnt) {
  int wid = (blockIdx.x * 256 + threadIdx.x) >> 6;
  int c = threadIdx.x & 63;
  int n0 = wid * 32;
  if (n0 >= NN) return;
  int nend = n0 + 32 < NN ? n0 + 32 : NN;
  int cur_b = batch[n0];
  float acc = 0.f, cacc = 0.f;
  for (int n = n0; n < nend; ++n) {
    int b = batch[n];
    if (b != cur_b) {
      atomicAdd(&g_sum[cur_b * 64 + c], acc);
      if (c == 0) atomicAdd(&cnt[cur_b], cacc);
      acc = 0.f;
      cacc = 0.f;
      cur_b = b;
    }
    acc += x[n * 64 + c];
    cacc += 1.f;
  }
  atomicAdd(&g_sum[cur_b * 64 + c], acc);
  if (c == 0) atomicAdd(&cnt[cur_b], cacc);
}

__global__ __launch_bounds__(64) void readout_kernel(
    const float* __restrict__ g_sum, const float* __restrict__ cnt,
    const float* __restrict__ Wm1, const float* __restrict__ bm1,
    const float* __restrict__ Wm2, const float* __restrict__ bm2,
    float* __restrict__ out) {
  int g = blockIdx.x;
  int t = threadIdx.x;
  float cv = fmaxf(cnt[g], 1.f);
  float gv = g_sum[g * 64 + t] / cv;
  float acc = 0.f;
#pragma unroll
  for (int k = 0; k < 64; ++k) {
    float bk = __shfl(gv, k);
    if (t < 32) acc += bk * Wm1[k * 32 + t];
  }
  float m = 0.f;
  if (t < 32) {
    float hid = fmaxf(acc + bm1[t], 0.f);
    m = hid * Wm2[t];
  }
  for (int off = 32; off >= 1; off >>= 1) m += __shfl_xor(m, off);
  if (t == 0) out[g] = m + bm2[0];
}

// ---------------- launch ----------------

extern "C" void kernel_launch(void* const* d_in, const int* in_sizes, int n_in,
                              void* d_out, int out_size, void* d_ws, size_t ws_size,
                              hipStream_t stream) {
  const float* x0       = (const float*)d_in[0];
  const int*   edge_idx = (const int*)d_in[1];
  const int*   batch    = (const int*)d_in[3];
  const int*   dis_idx  = (const int*)d_in[6];
  const float* W1  = (const float*)d_in[7];
  const float* as1 = (const float*)d_in[8];
  const float* ad1 = (const float*)d_in[9];
  const float* b1  = (const float*)d_in[10];
  const float* W2  = (const float*)d_in[11];
  const float* as2 = (const float*)d_in[12];
  const float* ad2 = (const float*)d_in[13];
  const float* b2  = (const float*)d_in[14];
  const float* Wm1 = (const float*)d_in[19];
  const float* bm1 = (const float*)d_in[20];
  const float* Wm2 = (const float*)d_in[21];
  const float* bm2 = (const float*)d_in[22];
  float* out = (float*)d_out;

  char* ws = (char*)d_ws;
  size_t off = 0;
  auto alloc = [&](size_t bytes) {
    void* p = ws + off;
    off += (bytes + 255) & ~(size_t)255;
    return p;
  };
  float* hA    = (float*)alloc(NN * 64 * 4);
  float* hB    = (float*)alloc(NN * 64 * 4);
  float* xF    = (float*)alloc(NN * 64 * 4);
  float* asA   = (float*)alloc(NN * 8 * 4);
  float* adA   = (float*)alloc(NN * 8 * 4);
  float* asB   = (float*)alloc(NN * 8 * 4);
  float* adB   = (float*)alloc(NN * 8 * 4);
  int* rp_d    = (int*)alloc((NN + 1) * 4);
  int* s_d     = (int*)alloc(NE * 4);
  int* rp_e    = (int*)alloc((NN + 1) * 4);
  int* s_e     = (int*)alloc(NE * 4);
  int* cnts    = (int*)alloc(NN * 4);
  float* g_sum = (float*)alloc(NG * 64 * 4);
  float* gcnt  = (float*)alloc(NG * 4);

  const int EB = (NE + 255) / 256;
  const int NB = NN / 4;
  const size_t SH = 64 * 64 * sizeof(float);

  // CSR for dis_index
  hipMemsetAsync(cnts, 0, NN * 4, stream);
  hist_kernel<<<EB, 256, 0, stream>>>(dis_idx + NE, cnts);
  scan_kernel<<<1, 1024, 0, stream>>>(cnts, rp_d);
  hipMemsetAsync(cnts, 0, NN * 4, stream);
  scatter_kernel<<<EB, 256, 0, stream>>>(dis_idx, dis_idx + NE, rp_d, cnts, s_d);

  // CSR for edge_index
  hipMemsetAsync(cnts, 0, NN * 4, stream);
  hist_kernel<<<EB, 256, 0, stream>>>(edge_idx + NE, cnts);
  scan_kernel<<<1, 1024, 0, stream>>>(cnts, rp_e);
  hipMemsetAsync(cnts, 0, NN * 4, stream);
  scatter_kernel<<<EB, 256, 0, stream>>>(edge_idx, edge_idx + NE, rp_e, cnts, s_e);

  // first conv1 GEMM + attention sums
  gemm_attn_kernel<<<NB, 256, 0, stream>>>(x0, W1, as1, ad1, hA, asA, adA, 8);

  // 12 convs; odd = conv1 (H=8, relu, fuse W2), even = conv2 (H=1, fuse W1)
  const int* rps[12] = {rp_d, rp_d, rp_e, rp_e, rp_d, rp_d, rp_e, rp_e, rp_d, rp_d, rp_e, rp_e};
  const int* sss[12] = {s_d, s_d, s_e, s_e, s_d, s_d, s_e, s_e, s_d, s_d, s_e, s_e};

  for (int k = 0; k < 12; ++k) {
    if ((k & 1) == 0) {
      // conv1: H=8, relu, next = conv2 (HN=1, W2)
      agg_fused_kernel<8, true, 1><<<NB, 256, SH, stream>>>(
          hA, asA, adA, rps[k], sss[k], b1, hB, W2, as2, ad2, asB, adB);
    } else if (k < 11) {
      // conv2: H=1, no relu, next = conv1 (HN=8, W1)
      agg_fused_kernel<1, false, 8><<<NB, 256, SH, stream>>>(
          hB, asB, adB, rps[k], sss[k], b2, hA, W1, as1, ad1, asA, adA);
    } else {
      // final conv2: write x
      agg_fused_kernel<1, false, 0><<<NB, 256, 0, stream>>>(
          hB, asB, adB, rps[k], sss[k], b2, xF, nullptr, nullptr, nullptr,
          nullptr, nullptr);
    }
  }

  // global mean pool + readout
  hipMemsetAsync(g_sum, 0, NG * 64 * 4, stream);
  hipMemsetAsync(gcnt, 0, NG * 4, stream);
  pool_kernel<<<(NN / 32 + 3) / 4, 256, 0, stream>>>(xF, batch, g_sum, gcnt);
  readout_kernel<<<NG, 64, 0, stream>>>(g_sum, gcnt, Wm1, bm1, Wm2, bm2, out);
}